// Round 1
// baseline (12629.296 us; speedup 1.0000x reference)
//
#include <hip/hip_runtime.h>
#include <hip/hip_bf16.h>
#include <stdint.h>

// RNN: h_t = relu(xs_t @ W_ih^T + h_{t-1} @ W_hh^T); ys = (h_seq @ W_out^T) transposed to [B,T,O]
// Pipeline: [gemm P=xs@Wih^T -> bf16 ws] -> [persistent recurrence kernel, 511 grid barriers,
//           in-place P_t -> h_t] -> [gemm out = h_seq@Wout^T with [T,B]->[B,T] store]
// All matmuls bf16 MFMA 16x16x32, f32 accumulate. ws = 128 MiB hseq + 4 B barrier counter.

#define TT 512
#define BB 64
#define NIN 1024
#define NH 2048
#define NOUT 1024
#define RNB 128   // recurrence grid blocks

typedef __attribute__((ext_vector_type(8))) short bf8;
typedef __attribute__((ext_vector_type(4))) float f4;
typedef __attribute__((ext_vector_type(4))) unsigned int u4;

static __device__ __forceinline__ unsigned short f2bf(float f) {
  __hip_bfloat16 h = __float2bfloat16(f);
  return __builtin_bit_cast(unsigned short, h);
}
static __device__ __forceinline__ float bf2f(unsigned short v) {
  return __bfloat162float(__builtin_bit_cast(__hip_bfloat16, v));
}
static __device__ __forceinline__ u4 pack8(const float* f) {
  u4 r;
#pragma unroll
  for (int i = 0; i < 4; ++i) {
    unsigned lo = f2bf(f[2 * i]);
    unsigned hi = f2bf(f[2 * i + 1]);
    r[i] = lo | (hi << 16);
  }
  return r;
}

// ---------------- generic C[M,N] = A[M,K] * B[N,K]^T (bf16 MFMA) ----------------
// ABF: A is bf16 (else f32, converted on the fly). B always f32 weights.
// TRANS: store f32 to out[(m&63)*TT*NOUT + (m>>6)*NOUT + n]; else store bf16 C[m*N+n].
template <bool ABF, bool TRANS>
__global__ void gemm_bt(const void* __restrict__ Av, const float* __restrict__ Bw,
                        void* __restrict__ Cv, int M, int N, int K) {
  constexpr int BM = 128, BN = 128, BK = 32;
  __shared__ u4 As[BM * 4];  // 8 KiB, 16B chunks, XOR-swizzled
  __shared__ u4 Bs[BN * 4];
  const int nt = N / BN;
  const int mi = (int)blockIdx.x / nt;
  const int ni = (int)blockIdx.x % nt;
  const int m0 = mi * BM, n0 = ni * BN;
  const int t = threadIdx.x;
  const int l = t & 63, w = t >> 6, wr = w >> 1, wc = w & 1;
  const int lr = l & 15, lq = l >> 4;

  f4 acc[4][4] = {};

  const int srow = t >> 1;        // staging row 0..127 (2 threads/row)
  const int sc0 = (t & 1) * 2;    // first of 2 chunks (chunk = 8 elems = 16B bf16)

  for (int kt = 0; kt < K; kt += BK) {
    // ---- stage A ----
    if (ABF) {
      const unsigned short* A = (const unsigned short*)Av;
#pragma unroll
      for (int cc = 0; cc < 2; ++cc) {
        int c = sc0 + cc;
        u4 v = *(const u4*)(A + (size_t)(m0 + srow) * K + kt + c * 8);
        As[srow * 4 + (c ^ ((srow ^ (srow >> 2)) & 3))] = v;
      }
    } else {
      const float* A = (const float*)Av;
#pragma unroll
      for (int cc = 0; cc < 2; ++cc) {
        int c = sc0 + cc;
        const float* p = A + (size_t)(m0 + srow) * K + kt + c * 8;
        float4 v0 = *(const float4*)p;
        float4 v1 = *(const float4*)(p + 4);
        float f[8] = {v0.x, v0.y, v0.z, v0.w, v1.x, v1.y, v1.z, v1.w};
        As[srow * 4 + (c ^ ((srow ^ (srow >> 2)) & 3))] = pack8(f);
      }
    }
    // ---- stage B (f32 weights) ----
#pragma unroll
    for (int cc = 0; cc < 2; ++cc) {
      int c = sc0 + cc;
      const float* p = Bw + (size_t)(n0 + srow) * K + kt + c * 8;
      float4 v0 = *(const float4*)p;
      float4 v1 = *(const float4*)(p + 4);
      float f[8] = {v0.x, v0.y, v0.z, v0.w, v1.x, v1.y, v1.z, v1.w};
      Bs[srow * 4 + (c ^ ((srow ^ (srow >> 2)) & 3))] = pack8(f);
    }
    __syncthreads();

    bf8 a[4], b[4];
#pragma unroll
    for (int i = 0; i < 4; ++i) {
      int ra = wr * 64 + i * 16 + lr;
      a[i] = __builtin_bit_cast(bf8, As[ra * 4 + (lq ^ ((ra ^ (ra >> 2)) & 3))]);
      int rb = wc * 64 + i * 16 + lr;
      b[i] = __builtin_bit_cast(bf8, Bs[rb * 4 + (lq ^ ((rb ^ (rb >> 2)) & 3))]);
    }
#pragma unroll
    for (int i = 0; i < 4; ++i)
#pragma unroll
      for (int j = 0; j < 4; ++j)
        acc[i][j] = __builtin_amdgcn_mfma_f32_16x16x32_bf16(a[i], b[j], acc[i][j], 0, 0, 0);
    __syncthreads();
  }

  // ---- epilogue: C/D layout col = l&15, row = (l>>4)*4 + r ----
  if (TRANS) {
    float* C = (float*)Cv;
#pragma unroll
    for (int i = 0; i < 4; ++i)
#pragma unroll
      for (int j = 0; j < 4; ++j)
#pragma unroll
        for (int r = 0; r < 4; ++r) {
          int m = m0 + wr * 64 + i * 16 + lq * 4 + r;
          int n = n0 + wc * 64 + j * 16 + lr;
          C[(size_t)(m & 63) * (TT * NOUT) + (size_t)(m >> 6) * NOUT + n] = acc[i][j][r];
        }
  } else {
    unsigned short* C = (unsigned short*)Cv;
#pragma unroll
    for (int i = 0; i < 4; ++i)
#pragma unroll
      for (int j = 0; j < 4; ++j)
#pragma unroll
        for (int r = 0; r < 4; ++r) {
          int m = m0 + wr * 64 + i * 16 + lq * 4 + r;
          int n = n0 + wc * 64 + j * 16 + lr;
          C[(size_t)m * N + n] = f2bf(acc[i][j][r]);
        }
  }
}

// ---------------- grid barrier (monotone counter, agent scope) ----------------
static __device__ __forceinline__ void gbar(unsigned* cnt, unsigned target) {
  __syncthreads();
  if (threadIdx.x == 0) {
    __threadfence();  // release our block's h-writes
    __hip_atomic_fetch_add(cnt, 1u, __ATOMIC_RELEASE, __HIP_MEMORY_SCOPE_AGENT);
    long spins = 0;
    while (__hip_atomic_load(cnt, __ATOMIC_RELAXED, __HIP_MEMORY_SCOPE_AGENT) < target) {
      __builtin_amdgcn_s_sleep(2);
      if (++spins > (1L << 22)) break;  // hang safety (never hit when logic is correct)
    }
    __threadfence();  // acquire: invalidate stale caches before reading others' h
  }
  __syncthreads();
}

// ---------------- persistent recurrence kernel ----------------
// hseq[t][b][j] (bf16) holds P (pre-activations) on entry; overwritten in place with h_t.
// Block owns j-slice [j0, j0+16); W_hh slice lives in swizzled LDS (64 KiB) for all 512 steps.
__global__ void rnn_recur(unsigned short* __restrict__ hseq, const float* __restrict__ Whh,
                          unsigned* __restrict__ cnt) {
  __shared__ u4 Wl[16 * 256];  // [j_local][chunk of 8 bf16], chunk XOR (j&7) swizzle
  const int t = threadIdx.x;
  const int j0 = (int)blockIdx.x * 16;

  // one-time: load + convert W_hh slice into LDS
  {
    const int jl = t >> 4;
    const int cbase = (t & 15) * 16;
    const float* src = Whh + (size_t)(j0 + jl) * NH + cbase * 8;
#pragma unroll
    for (int c = 0; c < 16; ++c) {
      const float* p = src + c * 8;
      float4 v0 = *(const float4*)p;
      float4 v1 = *(const float4*)(p + 4);
      float f[8] = {v0.x, v0.y, v0.z, v0.w, v1.x, v1.y, v1.z, v1.w};
      Wl[jl * 256 + ((cbase + c) ^ (jl & 7))] = pack8(f);
    }
  }

  const int l = t & 63, w = t >> 6;  // wave w owns b-rows [w*16, w*16+16)
  const int lr = l & 15, lq = l >> 4;

  // t = 0: h_0 = relu(P_0) in place (bf16 sign-bit relu is exact)
#pragma unroll
  for (int r = 0; r < 4; ++r) {
    int b = w * 16 + lq * 4 + r;
    size_t idx = (size_t)b * NH + j0 + lr;
    unsigned short v = hseq[idx];
    hseq[idx] = (v & 0x8000u) ? (unsigned short)0 : v;
  }

  for (int ts = 1; ts < TT; ++ts) {
    gbar(cnt, (unsigned)ts * RNB);
    // a-frag: h[ts-1][w*16 + lr][k + lq*8] straight from global
    const unsigned short* hp =
        hseq + (size_t)(ts - 1) * (BB * NH) + (size_t)(w * 16 + lr) * NH + lq * 8;
    f4 acc[8] = {};
#pragma unroll
    for (int ko = 0; ko < NH; ko += 256) {
#pragma unroll
      for (int u = 0; u < 8; ++u) {
        int k0 = ko + u * 32;
        bf8 a = *(const bf8*)(hp + k0);
        bf8 b = __builtin_bit_cast(bf8, Wl[lr * 256 + (((k0 >> 3) + lq) ^ (lr & 7))]);
        acc[u] = __builtin_amdgcn_mfma_f32_16x16x32_bf16(a, b, acc[u], 0, 0, 0);
      }
    }
    f4 s = ((acc[0] + acc[1]) + (acc[2] + acc[3])) + ((acc[4] + acc[5]) + (acc[6] + acc[7]));
#pragma unroll
    for (int r = 0; r < 4; ++r) {
      int b = w * 16 + lq * 4 + r;
      size_t idx = ((size_t)ts * BB + b) * NH + j0 + lr;
      float v = bf2f(hseq[idx]) + s[r];
      hseq[idx] = (v > 0.f) ? f2bf(v) : (unsigned short)0;
    }
  }
}

__global__ void kinit(unsigned* cnt) { *cnt = 0u; }

extern "C" void kernel_launch(void* const* d_in, const int* in_sizes, int n_in,
                              void* d_out, int out_size, void* d_ws, size_t ws_size,
                              hipStream_t stream) {
  const float* xs = (const float*)d_in[0];
  const float* Wih = (const float*)d_in[1];
  const float* Whh = (const float*)d_in[2];
  const float* Wout = (const float*)d_in[3];

  unsigned short* hseq = (unsigned short*)d_ws;  // [TT][BB][NH] bf16 = 128 MiB
  unsigned* cnt = (unsigned*)((char*)d_ws + (size_t)TT * BB * NH * 2);

  kinit<<<1, 1, 0, stream>>>(cnt);

  // phase 1: P = xs @ W_ih^T  -> bf16 hseq
  gemm_bt<false, false><<<(TT * BB / 128) * (NH / 128), 256, 0, stream>>>(
      (const void*)xs, Wih, (void*)hseq, TT * BB, NH, NIN);

  // phase 2: recurrence, in place
  rnn_recur<<<RNB, 256, 0, stream>>>(hseq, Whh, cnt);

  // phase 3: out[b][t][o] = h_seq @ W_out^T
  gemm_bt<true, true><<<(TT * BB / 128) * (NOUT / 128), 256, 0, stream>>>(
      (const void*)hseq, Wout, d_out, TT * BB, NOUT, NH);
}

// Round 2
// 9239.621 us; speedup vs baseline: 1.3669x; 1.3669x over previous
//
#include <hip/hip_runtime.h>
#include <hip/hip_bf16.h>
#include <stdint.h>

// RNN: h_t = relu(xs_t @ W_ih^T + h_{t-1} @ W_hh^T); ys = (h_seq @ W_out^T) transposed to [B,T,O]
// Phase 1: P = xs@Wih^T -> bf16 ws. Phase 2: persistent recurrence, 511 grid barriers,
// in-place P_t -> h_t. Phase 3: out = h_seq@Wout^T with [T,B]->[B,T] store.
// R2: recurrence rebuilt for memory-level parallelism: 16 waves/block (4 b-groups x 4 k-quarters),
// LDS cross-k reduction, P prefetched into regs before the barrier spin.

#define TT 512
#define BB 64
#define NIN 1024
#define NH 2048
#define NOUT 1024
#define RNB 128   // recurrence grid blocks (16 j-cols each)

typedef __attribute__((ext_vector_type(8))) short bf8;
typedef __attribute__((ext_vector_type(4))) float f4;
typedef __attribute__((ext_vector_type(4))) unsigned int u4;

static __device__ __forceinline__ unsigned short f2bf(float f) {
  __hip_bfloat16 h = __float2bfloat16(f);
  return __builtin_bit_cast(unsigned short, h);
}
static __device__ __forceinline__ float bf2f(unsigned short v) {
  return __bfloat162float(__builtin_bit_cast(__hip_bfloat16, v));
}
static __device__ __forceinline__ u4 pack8(const float* f) {
  u4 r;
#pragma unroll
  for (int i = 0; i < 4; ++i) {
    unsigned lo = f2bf(f[2 * i]);
    unsigned hi = f2bf(f[2 * i + 1]);
    r[i] = lo | (hi << 16);
  }
  return r;
}

// ---------------- generic C[M,N] = A[M,K] * B[N,K]^T (bf16 MFMA) ----------------
template <bool ABF, bool TRANS>
__global__ void gemm_bt(const void* __restrict__ Av, const float* __restrict__ Bw,
                        void* __restrict__ Cv, int M, int N, int K) {
  constexpr int BM = 128, BN = 128, BK = 32;
  __shared__ u4 As[BM * 4];
  __shared__ u4 Bs[BN * 4];
  const int nt = N / BN;
  const int mi = (int)blockIdx.x / nt;
  const int ni = (int)blockIdx.x % nt;
  const int m0 = mi * BM, n0 = ni * BN;
  const int t = threadIdx.x;
  const int l = t & 63, w = t >> 6, wr = w >> 1, wc = w & 1;
  const int lr = l & 15, lq = l >> 4;

  f4 acc[4][4] = {};

  const int srow = t >> 1;
  const int sc0 = (t & 1) * 2;

  for (int kt = 0; kt < K; kt += BK) {
    if (ABF) {
      const unsigned short* A = (const unsigned short*)Av;
#pragma unroll
      for (int cc = 0; cc < 2; ++cc) {
        int c = sc0 + cc;
        u4 v = *(const u4*)(A + (size_t)(m0 + srow) * K + kt + c * 8);
        As[srow * 4 + (c ^ ((srow ^ (srow >> 2)) & 3))] = v;
      }
    } else {
      const float* A = (const float*)Av;
#pragma unroll
      for (int cc = 0; cc < 2; ++cc) {
        int c = sc0 + cc;
        const float* p = A + (size_t)(m0 + srow) * K + kt + c * 8;
        float4 v0 = *(const float4*)p;
        float4 v1 = *(const float4*)(p + 4);
        float f[8] = {v0.x, v0.y, v0.z, v0.w, v1.x, v1.y, v1.z, v1.w};
        As[srow * 4 + (c ^ ((srow ^ (srow >> 2)) & 3))] = pack8(f);
      }
    }
#pragma unroll
    for (int cc = 0; cc < 2; ++cc) {
      int c = sc0 + cc;
      const float* p = Bw + (size_t)(n0 + srow) * K + kt + c * 8;
      float4 v0 = *(const float4*)p;
      float4 v1 = *(const float4*)(p + 4);
      float f[8] = {v0.x, v0.y, v0.z, v0.w, v1.x, v1.y, v1.z, v1.w};
      Bs[srow * 4 + (c ^ ((srow ^ (srow >> 2)) & 3))] = pack8(f);
    }
    __syncthreads();

    bf8 a[4], b[4];
#pragma unroll
    for (int i = 0; i < 4; ++i) {
      int ra = wr * 64 + i * 16 + lr;
      a[i] = __builtin_bit_cast(bf8, As[ra * 4 + (lq ^ ((ra ^ (ra >> 2)) & 3))]);
      int rb = wc * 64 + i * 16 + lr;
      b[i] = __builtin_bit_cast(bf8, Bs[rb * 4 + (lq ^ ((rb ^ (rb >> 2)) & 3))]);
    }
#pragma unroll
    for (int i = 0; i < 4; ++i)
#pragma unroll
      for (int j = 0; j < 4; ++j)
        acc[i][j] = __builtin_amdgcn_mfma_f32_16x16x32_bf16(a[i], b[j], acc[i][j], 0, 0, 0);
    __syncthreads();
  }

  if (TRANS) {
    float* C = (float*)Cv;
#pragma unroll
    for (int i = 0; i < 4; ++i)
#pragma unroll
      for (int j = 0; j < 4; ++j)
#pragma unroll
        for (int r = 0; r < 4; ++r) {
          int m = m0 + wr * 64 + i * 16 + lq * 4 + r;
          int n = n0 + wc * 64 + j * 16 + lr;
          C[(size_t)(m & 63) * (TT * NOUT) + (size_t)(m >> 6) * NOUT + n] = acc[i][j][r];
        }
  } else {
    unsigned short* C = (unsigned short*)Cv;
#pragma unroll
    for (int i = 0; i < 4; ++i)
#pragma unroll
      for (int j = 0; j < 4; ++j)
#pragma unroll
        for (int r = 0; r < 4; ++r) {
          int m = m0 + wr * 64 + i * 16 + lq * 4 + r;
          int n = n0 + wc * 64 + j * 16 + lr;
          C[(size_t)m * N + n] = f2bf(acc[i][j][r]);
        }
  }
}

// ---------------- grid barrier (monotone counter, agent scope) ----------------
static __device__ __forceinline__ void gbar(unsigned* cnt, unsigned target) {
  __syncthreads();
  if (threadIdx.x == 0) {
    __threadfence();  // release our block's h-writes
    __hip_atomic_fetch_add(cnt, 1u, __ATOMIC_RELEASE, __HIP_MEMORY_SCOPE_AGENT);
    long spins = 0;
    while (__hip_atomic_load(cnt, __ATOMIC_RELAXED, __HIP_MEMORY_SCOPE_AGENT) < target) {
      __builtin_amdgcn_s_sleep(2);
      if (++spins > (1L << 22)) break;  // hang safety
    }
    __threadfence();  // acquire: invalidate stale caches before reading others' h
  }
  __syncthreads();
}

// ---------------- persistent recurrence kernel ----------------
// 16 waves: wave w -> b-group bg=w&3 (rows bg*16..+15), k-quarter kg=w>>2 (k in kg*512..+511).
// Block owns j-slice [j0, j0+16); W_hh slice in swizzled LDS. Cross-kg reduce via padded LDS.
// P (pre-activation) for the NEXT step is prefetched into regs before the barrier spin.
__global__ __launch_bounds__(1024, 4) void rnn_recur(unsigned short* __restrict__ hseq,
                                                     const float* __restrict__ Whh,
                                                     unsigned* __restrict__ cnt) {
  __shared__ u4 Wl[16 * 256];            // 64 KiB: [j_local][k-chunk of 8 bf16], chunk ^ (j&7)
  __shared__ float red[3 * 4 * 16 * 17]; // 13 KiB: [kg-1][bg][brow 16][j 16+pad]
  const int t = threadIdx.x;
  const int j0 = (int)blockIdx.x * 16;

  // one-time: load + convert W_hh slice into LDS (1024 threads, 4 chunks each)
  {
    const int jl = t >> 6;          // 0..15
    const int c0 = (t & 63) * 4;    // 4 chunks of 8 elems
#pragma unroll
    for (int c = 0; c < 4; ++c) {
      int cc = c0 + c;
      const float* p = Whh + (size_t)(j0 + jl) * NH + cc * 8;
      float4 v0 = *(const float4*)p;
      float4 v1 = *(const float4*)(p + 4);
      float f[8] = {v0.x, v0.y, v0.z, v0.w, v1.x, v1.y, v1.z, v1.w};
      Wl[jl * 256 + (cc ^ (jl & 7))] = pack8(f);
    }
  }

  const int l = t & 63, w = t >> 6;
  const int lr = l & 15, lq = l >> 4;
  const int bg = w & 3, kg = w >> 2;

  float pre[4] = {0.f, 0.f, 0.f, 0.f};  // prefetched P for next step (kg==0 waves only)

  // t = 0: h_0 = relu(P_0) in place (sign-bit relu exact in bf16); prefetch P_1
  if (kg == 0) {
#pragma unroll
    for (int r = 0; r < 4; ++r) {
      int b = bg * 16 + lq * 4 + r;
      size_t idx = (size_t)b * NH + j0 + lr;
      unsigned short v = hseq[idx];
      hseq[idx] = (v & 0x8000u) ? (unsigned short)0 : v;
      pre[r] = bf2f(hseq[(size_t)(1 * BB + b) * NH + j0 + lr]);
    }
  }

  for (int ts = 1; ts < TT; ++ts) {
    gbar(cnt, (unsigned)ts * RNB);

    // a-frags: h[ts-1][bg*16+lr][kg*512 + lq*8 + ...], two 8-deep load batches
    const unsigned short* hp = hseq + (size_t)(ts - 1) * (BB * NH) +
                               (size_t)(bg * 16 + lr) * NH + kg * 512 + lq * 8;
    f4 acc[2] = {};
#pragma unroll
    for (int half = 0; half < 2; ++half) {
      const int kb = half * 256;
      bf8 af[8];
#pragma unroll
      for (int u = 0; u < 8; ++u) af[u] = *(const bf8*)(hp + kb + u * 32);
#pragma unroll
      for (int u = 0; u < 8; ++u) {
        int c = ((kg * 512 + kb + u * 32) >> 3) + lq;
        bf8 bfr = __builtin_bit_cast(bf8, Wl[lr * 256 + (c ^ (lr & 7))]);
        acc[u & 1] = __builtin_amdgcn_mfma_f32_16x16x32_bf16(af[u], bfr, acc[u & 1], 0, 0, 0);
      }
    }
    f4 a2 = acc[0] + acc[1];

    if (kg) {
      const int base = ((kg - 1) * 4 + bg) * (16 * 17);
#pragma unroll
      for (int r = 0; r < 4; ++r) red[base + (lq * 4 + r) * 17 + lr] = a2[r];
    }
    __syncthreads();

    if (kg == 0) {
      const int rb = bg * (16 * 17);
#pragma unroll
      for (int r = 0; r < 4; ++r) {
        int ro = (lq * 4 + r) * 17 + lr;
        float s = a2[r] + red[rb + ro] + red[4 * 272 + rb + ro] + red[8 * 272 + rb + ro] + pre[r];
        int b = bg * 16 + lq * 4 + r;
        hseq[((size_t)ts * BB + b) * NH + j0 + lr] = (s > 0.f) ? f2bf(s) : (unsigned short)0;
      }
      // prefetch P for step ts+1 (this slot is only ever written by THIS block, at step ts+1)
      if (ts + 1 < TT) {
#pragma unroll
        for (int r = 0; r < 4; ++r) {
          int b = bg * 16 + lq * 4 + r;
          pre[r] = bf2f(hseq[((size_t)(ts + 1) * BB + b) * NH + j0 + lr]);
        }
      }
    }
  }
}

__global__ void kinit(unsigned* cnt) { *cnt = 0u; }

extern "C" void kernel_launch(void* const* d_in, const int* in_sizes, int n_in,
                              void* d_out, int out_size, void* d_ws, size_t ws_size,
                              hipStream_t stream) {
  const float* xs = (const float*)d_in[0];
  const float* Wih = (const float*)d_in[1];
  const float* Whh = (const float*)d_in[2];
  const float* Wout = (const float*)d_in[3];

  unsigned short* hseq = (unsigned short*)d_ws;  // [TT][BB][NH] bf16 = 128 MiB
  unsigned* cnt = (unsigned*)((char*)d_ws + (size_t)TT * BB * NH * 2);

  kinit<<<1, 1, 0, stream>>>(cnt);

  gemm_bt<false, false><<<(TT * BB / 128) * (NH / 128), 256, 0, stream>>>(
      (const void*)xs, Wih, (void*)hseq, TT * BB, NH, NIN);

  rnn_recur<<<RNB, 1024, 0, stream>>>(hseq, Whh, cnt);

  gemm_bt<true, true><<<(TT * BB / 128) * (NOUT / 128), 256, 0, stream>>>(
      (const void*)hseq, Wout, d_out, TT * BB, NOUT, NH);
}